// Round 7
// baseline (639.993 us; speedup 1.0000x reference)
//
#include <hip/hip_runtime.h>
#include <math.h>

#define BATCH 32
#define T 2048
#define D 1024
#define KW 31
#define CPAD 15
#define KEXT 62      // 2*31 conv-patch columns
#define KTOT 1088    // 1024 + 64 (ext cols live in Amem/Bext tail)
#define BM 256
#define BN 256
#define KSTEP 64
#define NK (KTOT / KSTEP)   // 17

typedef __bf16 bf16_8 __attribute__((ext_vector_type(8)));
typedef __bf16 bf16_4 __attribute__((ext_vector_type(4)));
typedef float  f32x4  __attribute__((ext_vector_type(4)));

__device__ __forceinline__ float tanh_fast(float x) {
    return 1.f - 2.f * __builtin_amdgcn_rcpf(__expf(2.f * x) + 1.f);
}

__device__ __forceinline__ void glds16(const void* gsrc, void* ldst) {
    __builtin_amdgcn_global_load_lds(
        (const __attribute__((address_space(1))) unsigned int*)gsrc,
        (__attribute__((address_space(3))) unsigned int*)ldst, 16, 0, 0);
}

#define VM8 asm volatile("s_waitcnt vmcnt(8)" ::: "memory")
#define VM6 asm volatile("s_waitcnt vmcnt(6)" ::: "memory")
#define VM0 asm volatile("s_waitcnt vmcnt(0)" ::: "memory")
#define BAR __builtin_amdgcn_s_barrier()
#define PRIO1 __builtin_amdgcn_s_setprio(1)
#define PRIO0 __builtin_amdgcn_s_setprio(0)

// ---------------- P: merged prep (amem | q | aloc | b) ----------------
//   [0,4096)        : Amem[row][0:1024] = bf16(memory)
//   [4096,12288)    : qv = query @ Wq^T
//   [12288,16384)   : Amem[row][1024:1088] = bf16 conv patches
//   [16384,17472)   : Bext = bf16([Wm | Wloc])
#define PREP_BLOCKS 17472
__global__ __launch_bounds__(256) void k_prep_all(
    const float* __restrict__ Wm, const float* __restrict__ Wloc,
    __bf16* __restrict__ Bext,
    const float* __restrict__ memory, __bf16* __restrict__ Amem,
    const float* __restrict__ prev, const float* __restrict__ cum,
    const float* __restrict__ query, const float* __restrict__ Wq,
    float* __restrict__ qout) {
    const int gb = blockIdx.x;
    if (gb < 4096) {
        // ---- Amem body: 16 fp32 -> bf16 per thread, grid-stride ----
        const int nvec = BATCH * T * (D / 16);
        for (int idx = gb * 256 + threadIdx.x; idx < nvec; idx += 4096 * 256) {
            const int row = idx >> 6;              // b*T + t  (64 threads/row)
            const int c = (idx & 63) * 16;
            const float* src = memory + (size_t)row * D + c;
            const f32x4 a0 = *(const f32x4*)(src);
            const f32x4 a1 = *(const f32x4*)(src + 4);
            const f32x4 a2 = *(const f32x4*)(src + 8);
            const f32x4 a3 = *(const f32x4*)(src + 12);
            bf16_8 o0, o1;
            #pragma unroll
            for (int u = 0; u < 4; ++u) {
                o0[u] = (__bf16)a0[u]; o0[u + 4] = (__bf16)a1[u];
                o1[u] = (__bf16)a2[u]; o1[u + 4] = (__bf16)a3[u];
            }
            __bf16* dst = Amem + (size_t)row * KTOT + c;
            *(bf16_8*)(dst) = o0;
            *(bf16_8*)(dst + 8) = o1;
        }
    } else if (gb < 12288) {
        // ---- q = query @ Wq^T ----
        const int j = gb - 4096;
        const int xb = j & 255;
        const int b = j >> 8;
        const int w = threadIdx.x >> 6;
        const int lane = threadIdx.x & 63;
        const int d = xb * 4 + w;
        const float* qrow = query + (size_t)b * D;
        const float* wrow = Wq + (size_t)d * D;
        float s = 0.f;
        #pragma unroll
        for (int i = 0; i < D / 64; ++i) s += qrow[lane + i * 64] * wrow[lane + i * 64];
        #pragma unroll
        for (int off = 32; off > 0; off >>= 1) s += __shfl_down(s, off, 64);
        if (lane == 0) qout[(size_t)b * D + d] = s;
    } else if (gb < 16384) {
        // ---- Amem conv-ext tail ----
        const int idx = (gb - 12288) * 256 + threadIdx.x;
        const int row = idx >> 4;          // b*T + t
        const int j0 = (idx & 15) * 4;
        const int b = row >> 11;
        const int t = row & (T - 1);
        bf16_4 o;
        #pragma unroll
        for (int u = 0; u < 4; ++u) {
            const int jj = j0 + u;
            float val = 0.f;
            if (jj < KEXT) {
                const int c = (jj >= KW) ? 1 : 0;
                const int kp = jj - c * KW;
                const int ts = t + kp - CPAD;
                if (ts >= 0 && ts < T)
                    val = (c ? cum : prev)[(size_t)b * T + ts];
            }
            o[u] = (__bf16)val;
        }
        *(bf16_4*)(Amem + (size_t)row * KTOT + D + j0) = o;
    } else {
        // ---- Bext = bf16([Wm | Wloc]) ----
        const int idx = (gb - 16384) * 256 + threadIdx.x;
        const int d = idx / (KTOT / 4);
        const int kk = (idx % (KTOT / 4)) * 4;
        bf16_4 o;
        #pragma unroll
        for (int u = 0; u < 4; ++u) {
            const int k = kk + u;
            float val = 0.f;
            if (k < D) val = Wm[(size_t)d * D + k];
            else {
                const int jj = k - D;
                if (jj < KEXT) {
                    const int c = (jj >= KW) ? 1 : 0;
                    const int kp = jj - c * KW;
                    val = Wloc[((size_t)d * 2 + c) * KW + kp];
                }
            }
            o[u] = (__bf16)val;
        }
        *(bf16_4*)(Bext + (size_t)d * KTOT + kk) = o;
    }
}

// ---------------- K2: 256x256 phase-split MFMA GEMM + tanh*v epilogue ----------------
// r7 schedule: A0/B0 of tile k+2 issued at ph3(k) into the CURRENT buffer's
// A0/B0 slots (read-complete since ph0(k)) -> 4.5-phase cover and a ds_read-only
// ph0. B1(k+1)@ph1(k), A1(k+1)@ph2(k) (3-phase cover). Gates: VM6@ph0-end,
// VM6@ph1-end, VM8@ph3-end; never below 8 outstanding in the loop.
// XCD-aware swizzle: hw block id % 8 = XCD; each XCD owns whole A-panels
// (4 consecutive d-tiles of one (t,b) panel) for L2 reuse. 1024 = 8*128 exact.
__global__ __launch_bounds__(512, 2) void k_gemm_e(
    const __bf16* __restrict__ Amem, const __bf16* __restrict__ Bext,
    const float* __restrict__ qv, const float* __restrict__ vvec,
    float* __restrict__ e_part) {
    __shared__ bf16_8 As[2][2048];   // 2 x 32 KB  (32 slots x 64 lanes)
    __shared__ bf16_8 Bs[2][2048];   // 2 x 32 KB  -> 128 KB total

    // XCD swizzle: hw id -> logical (b, t-tile, d-tile) with d fastest
    const int hw = blockIdx.x + 8 * (blockIdx.y + 4 * blockIdx.z);  // 0..1023
    const int logical = (hw & 7) * 128 + (hw >> 3);
    const int b  = logical >> 5;         // 0..31
    const int r  = logical & 31;
    const int t0 = (r >> 2) * BM;        // t-tile 0..7
    const int dt = r & 3;                // d-tile 0..3
    const int d0 = dt * BN;

    const int tid  = threadIdx.x;
    const int lane = tid & 63;
    const int w    = tid >> 6;     // 0..7
    const int wm   = w >> 2;       // 0..1  (row-wave)
    const int wn   = w & 3;        // 0..3  (col-wave)
    const int ml   = lane & 15;
    const int qk   = lane >> 4;

    f32x4 acc[8][4] = {};

    const __bf16* gA[2][2];
    const __bf16* gB[2][2];
    int sA[2][2], sB[2][2];
    #pragma unroll
    for (int h = 0; h < 2; ++h) {
        #pragma unroll
        for (int j = 0; j < 2; ++j) {
            const int idx = j * 8 + w;
            const int p = idx >> 1, kfa = idx & 1;
            const int mf = h * 4 + (p & 3) + (idx & 8);
            const int nf = h * 2 + (p & 1) + (p >> 1) * 4;
            gA[h][j] = Amem + ((size_t)b * T + t0 + mf * 16 + ml) * KTOT + kfa * 32 + qk * 8;
            sA[h][j] = (mf * 2 + kfa) * 64;
            gB[h][j] = Bext + (size_t)(d0 + nf * 16 + ml) * KTOT + kfa * 32 + qk * 8;
            sB[h][j] = (nf * 2 + kfa) * 64;
        }
    }

    bf16_8 areg[4][2];               // current A quadrant (overwritten at ph2)
    bf16_8 breg0[2][2], breg1[2][2]; // B halves jh=0 / jh=1

    auto STG_A = [&](int h, int kcol, bf16_8* dst) {
        glds16(gA[h][0] + kcol, dst + sA[h][0]);
        glds16(gA[h][1] + kcol, dst + sA[h][1]);
    };
    auto STG_B = [&](int h, int kcol, bf16_8* dst) {
        glds16(gB[h][0] + kcol, dst + sB[h][0]);
        glds16(gB[h][1] + kcol, dst + sB[h][1]);
    };
    auto LDA = [&](const bf16_8* buf, int ih) {
        #pragma unroll
        for (int i = 0; i < 4; ++i)
            #pragma unroll
            for (int kf = 0; kf < 2; ++kf)
                areg[i][kf] = buf[((wm * 8 + ih * 4 + i) * 2 + kf) * 64 + lane];
    };
    auto LDB = [&](bf16_8 (&dst)[2][2], const bf16_8* buf, int jh) {
        #pragma unroll
        for (int j = 0; j < 2; ++j)
            #pragma unroll
            for (int kf = 0; kf < 2; ++kf)
                dst[j][kf] = buf[((wn * 4 + jh * 2 + j) * 2 + kf) * 64 + lane];
    };
    auto QMM = [&](bf16_8 (&bb)[2][2], int ih, int jh) {
        #pragma unroll
        for (int i = 0; i < 4; ++i)
            #pragma unroll
            for (int kf = 0; kf < 2; ++kf)
                #pragma unroll
                for (int j = 0; j < 2; ++j)
                    acc[ih * 4 + i][jh * 2 + j] = __builtin_amdgcn_mfma_f32_16x16x32_bf16(
                        areg[i][kf], bb[j][kf], acc[ih * 4 + i][jh * 2 + j], 0, 0, 0);
    };

    // ---- prologue: tile0 {A0,B0,B1,A1} + pre-issue tile1 {A0,B0} (12 loads) ----
    STG_A(0, 0, As[0]);
    STG_B(0, 0, Bs[0]);
    STG_B(1, 0, Bs[0]);
    STG_A(1, 0, As[0]);
    STG_A(0, KSTEP, As[1]);
    STG_B(0, KSTEP, Bs[1]);
    VM8;                 // drains A0(0),B0(0); 8 left in flight
    BAR;

    #pragma unroll 1
    for (int k = 0; k < NK; ++k) {
        bf16_8* Ac = As[k & 1];
        bf16_8* Bc = Bs[k & 1];
        bf16_8* An = As[(k + 1) & 1];
        bf16_8* Bn = Bs[(k + 1) & 1];
        const int c1 = ((k + 1 < NK) ? (k + 1) : 0) * KSTEP;   // dead-wrap tail
        const int c2 = ((k + 2 < NK) ? (k + 2) : 0) * KSTEP;
        // ph0: quad(0,0). reads A0(k),B0(k) [drained ph3-end of k-1]. no issues.
        LDA(Ac, 0);
        LDB(breg0, Bc, 0);
        BAR;
        PRIO1; QMM(breg0, 0, 0); PRIO0;
        VM6;                         // drains B1(k)  [issued ph1(k-1), 3-ph cover]
        BAR;
        // ph1: quad(0,1). reads B1(k)
        LDB(breg1, Bc, 1);
        STG_B(1, c1, Bn);
        BAR;
        PRIO1; QMM(breg1, 0, 1); PRIO0;
        VM6;                         // drains A1(k)  [issued ph2(k-1), 3-ph cover]
        BAR;
        // ph2: quad(1,0). reads A1(k)
        LDA(Ac, 1);
        STG_A(1, c1, An);
        BAR;
        PRIO1; QMM(breg0, 1, 0); PRIO0;
        BAR;                         // no gate (ph3 reads no LDS)
        // ph3: quad(1,1). pure registers; issue A0/B0(k+2) into CURRENT buf's
        // A0/B0 slots (their reads completed at ph0(k); tile k+2 reads buf[k&1])
        STG_A(0, c2, Ac);
        STG_B(0, c2, Bc);
        PRIO1; QMM(breg1, 1, 1); PRIO0;
        VM8;                         // drains A0(k+1),B0(k+1) [4.5-ph cover]
        BAR;
    }
    VM0;   // drain dead-wrap loads
    BAR;   // all waves' dead-wrap writes landed; all LDS reads done

    // ---- epilogue: e(t) = sum_d tanh(acc + q[d]) * v[d], reduced over wn ----
    float qreg[4], vreg[4];
    #pragma unroll
    for (int jb = 0; jb < 4; ++jb) {
        const int d = d0 + wn * 64 + jb * 16 + ml;
        qreg[jb] = qv[(size_t)b * D + d];
        vreg[jb] = vvec[d];
    }
    float (*est)[256] = (float (*)[256])(&As[0][0]);   // overwritten after VM0+BAR
    #pragma unroll
    for (int ia = 0; ia < 8; ++ia) {
        #pragma unroll
        for (int r2 = 0; r2 < 4; ++r2) {
            float s = 0.f;
            #pragma unroll
            for (int jb = 0; jb < 4; ++jb)
                s += tanh_fast(acc[ia][jb][r2] + qreg[jb]) * vreg[jb];
            #pragma unroll
            for (int off = 8; off > 0; off >>= 1)
                s += __shfl_down(s, off, 16);
            if (ml == 0)
                est[wn][wm * 128 + ia * 16 + qk * 4 + r2] = s;
        }
    }
    __syncthreads();
    if (tid < 256) {
        const float e = est[0][tid] + est[1][tid] + est[2][tid] + est[3][tid];
        e_part[((size_t)b * T + t0 + tid) * 4 + dt] = e;
    }
}

// ---------------- K3: masked softmax over T (e_part [B,T,4]) ----------------
__global__ __launch_bounds__(256) void k_softmax(const float* __restrict__ e_part,
                                                 const int* __restrict__ mask,
                                                 float* __restrict__ aout) {
    const int b = blockIdx.x;
    const int tid = threadIdx.x;
    __shared__ float red[256];
    float ev[8];
    float lmax = -INFINITY;
    #pragma unroll
    for (int i = 0; i < 8; ++i) {
        const int t = tid + i * 256;
        const f32x4 p4 = *(const f32x4*)(e_part + ((size_t)b * T + t) * 4);
        float s = p4[0] + p4[1] + p4[2] + p4[3];
        if (mask[(size_t)b * T + t] != 0) s = -INFINITY;
        ev[i] = s;
        lmax = fmaxf(lmax, s);
    }
    red[tid] = lmax; __syncthreads();
    for (int off = 128; off > 0; off >>= 1) {
        if (tid < off) red[tid] = fmaxf(red[tid], red[tid + off]);
        __syncthreads();
    }
    const float mx = red[0]; __syncthreads();
    float lsum = 0.f;
    #pragma unroll
    for (int i = 0; i < 8; ++i) {
        const float x = expf(ev[i] - mx);
        ev[i] = x;
        lsum += x;
    }
    red[tid] = lsum; __syncthreads();
    for (int off = 128; off > 0; off >>= 1) {
        if (tid < off) red[tid] += red[tid + off];
        __syncthreads();
    }
    const float inv = 1.f / red[0];
    #pragma unroll
    for (int i = 0; i < 8; ++i)
        aout[(size_t)b * T + tid + i * 256] = ev[i] * inv;
}

// ---------------- K4: partial ctx from bf16 Amem, 16B loads, 2-way t-split ----------------
__global__ __launch_bounds__(256) void k_ctx_part(const __bf16* __restrict__ Amem,
                                                  const float* __restrict__ a,
                                                  float* __restrict__ ctx_part) {
    const int b = blockIdx.x;
    const int tc = blockIdx.y;           // 0..31, 64 t each
    const int th = threadIdx.x >> 7;     // t-half 0/1 (32 t each)
    const int cg = threadIdx.x & 127;    // col group
    const int d8 = cg * 8;
    __shared__ float red[128][8];
    float acc[8] = {};
    const int trow = tc * 64 + th * 32;
    const __bf16* mb = Amem + ((size_t)b * T + trow) * KTOT + d8;
    const float* ab = a + (size_t)b * T + trow;
    #pragma unroll 4
    for (int t = 0; t < 32; ++t) {
        const float wgt = ab[t];
        const bf16_8 m8 = *(const bf16_8*)(mb + (size_t)t * KTOT);
        #pragma unroll
        for (int u = 0; u < 8; ++u) acc[u] += wgt * (float)m8[u];
    }
    if (th == 1) {
        #pragma unroll
        for (int u = 0; u < 8; ++u) red[cg][u] = acc[u];
    }
    __syncthreads();
    if (th == 0) {
        f32x4 o0, o1;
        #pragma unroll
        for (int u = 0; u < 4; ++u) {
            o0[u] = acc[u] + red[cg][u];
            o1[u] = acc[u + 4] + red[cg][u + 4];
        }
        float* dst = ctx_part + ((size_t)(b * 32 + tc)) * D + d8;
        *(f32x4*)(dst) = o0;
        *(f32x4*)(dst + 4) = o1;
    }
}

// ---------------- K5: reduce 32 ctx partials ----------------
__global__ __launch_bounds__(256) void k_ctx_red(const float* __restrict__ ctx_part,
                                                 float* __restrict__ ctx) {
    const int idx = blockIdx.x * 256 + threadIdx.x;
    const int b = idx >> 10, d = idx & 1023;
    float s = 0.f;
    #pragma unroll
    for (int tc = 0; tc < 32; ++tc) s += ctx_part[((size_t)(b * 32 + tc)) * D + d];
    ctx[idx] = s;
}

extern "C" void kernel_launch(void* const* d_in, const int* in_sizes, int n_in,
                              void* d_out, int out_size, void* d_ws, size_t ws_size,
                              hipStream_t stream) {
    const float* query  = (const float*)d_in[0];
    const float* memory = (const float*)d_in[1];
    const float* prev   = (const float*)d_in[2];
    const float* cum    = (const float*)d_in[3];
    const int*   mask   = (const int*)d_in[4];
    const float* Wq     = (const float*)d_in[5];
    const float* Wm     = (const float*)d_in[6];
    const float* Wloc   = (const float*)d_in[7];
    const float* v      = (const float*)d_in[8];

    float* out = (float*)d_out;
    float* ctx = out;               // [B, D]
    float* a   = out + BATCH * D;   // [B, T]

    char* ws = (char*)d_ws;
    float*  qv       = (float*)(ws + 0);                 // 128 KB
    float*  e_part   = (float*)(ws + 131072);            // 1 MB   [B,T,4]
    float*  ctx_part = (float*)(ws + 4325376);           // 4 MB   [B,32,D]
    __bf16* Bext     = (__bf16*)(ws + 8519680);          // 2.23 MB [1024,1088]
    __bf16* Amem     = (__bf16*)(ws + 10747904);         // 136 MB  [B*T,1088] bf16
    // total ~146.3 MB

    k_prep_all<<<PREP_BLOCKS, 256, 0, stream>>>(Wm, Wloc, Bext, memory, Amem,
                                                prev, cum, query, Wq, qv);
    k_gemm_e<<<dim3(T / BM, D / BN, BATCH), 512, 0, stream>>>(Amem, Bext, qv, v, e_part);
    k_softmax<<<BATCH, 256, 0, stream>>>(e_part, mask, a);
    k_ctx_part<<<dim3(BATCH, 32), 256, 0, stream>>>(Amem, a, ctx_part);
    k_ctx_red<<<(BATCH * D) / 256, 256, 0, stream>>>(ctx_part, ctx);
}